// Round 7
// baseline (534.489 us; speedup 1.0000x reference)
//
#include <hip/hip_runtime.h>
#include <hip/hip_bf16.h>
#include <stdint.h>

typedef __attribute__((ext_vector_type(4))) float  f32x4;
typedef __attribute__((ext_vector_type(8))) short  s16x8;
typedef __attribute__((ext_vector_type(4))) short  s16x4;

constexpr int I_SZ = 2048;
constexpr int O_SZ = 2048;
constexpr int T_SZ = 2048;
constexpr int B_MAX = 16;

// pre-tiled layout: per (bz, mtile/ntile of 128, ktile of 32): 8KB block =
// 8 subtiles (16 rows each) x 1KB; within a subtile, byte offset l*16 holds
// fragment of lane l: row = l&15, k = 4*(l>>4) + {0..3} and 16 + 4*(l>>4) + {0..3}
constexpr size_t XT_ELEMS = (size_t)B_MAX * T_SZ * I_SZ;         // 67,108,864 shorts
constexpr size_t WT_ELEMS = (size_t)B_MAX * I_SZ * O_SZ;
constexpr size_t WS_NEEDED = (XT_ELEMS + WT_ELEMS) * sizeof(short); // 256 MB

__device__ __forceinline__ short f2bf(float f) {
    __hip_bfloat16 h = __float2bfloat16(f);
    return *reinterpret_cast<short*>(&h);
}

__device__ __forceinline__ void gload_lds16(const void* g, void* l) {
    __builtin_amdgcn_global_load_lds(
        (const __attribute__((address_space(1))) unsigned int*)g,
        (__attribute__((address_space(3))) unsigned int*)l, 16, 0, 0);
}

// ---------------- conversion: x fp32 [B][T][I] -> pre-tiled bf16 ----------------
__global__ __launch_bounds__(256) void convA(const float* __restrict__ x,
                                             short* __restrict__ xt) {
    const int c = blockIdx.x * 256 + threadIdx.x;    // 16B-chunk id
    const int l  = c & 63;
    const int mi = (c >> 6) & 7;
    const int kt = (c >> 9) & 63;
    const int rest = c >> 15;                        // (bz*16 + mt)
    const int mt = rest & 15, bz = rest >> 4;
    const int lr = l & 15, hi = l >> 4;
    const int m = mt * 128 + mi * 16 + lr;
    const float* src = x + ((size_t)(bz * T_SZ + m)) * I_SZ + kt * 32 + 4 * hi;
    f32x4 a = *reinterpret_cast<const f32x4*>(src);
    f32x4 b = *reinterpret_cast<const f32x4*>(src + 16);
    s16x8 h = { f2bf(a[0]), f2bf(a[1]), f2bf(a[2]), f2bf(a[3]),
                f2bf(b[0]), f2bf(b[1]), f2bf(b[2]), f2bf(b[3]) };
    *reinterpret_cast<s16x8*>(xt + (size_t)c * 8) = h;
}

// ------- conversion: W fp32 [dom][I][O] gathered+transposed -> pre-tiled bf16 ----
__global__ __launch_bounds__(256) void convB(const float* __restrict__ fcw,
                                             const int* __restrict__ dom_id,
                                             short* __restrict__ wt) {
    const int c = blockIdx.x * 256 + threadIdx.x;
    const int l  = c & 63;
    const int ni = (c >> 6) & 7;
    const int kt = (c >> 9) & 63;
    const int rest = c >> 15;                        // (bz*16 + nt)
    const int nt = rest & 15, bz = rest >> 4;
    const int lr = l & 15, hi = l >> 4;
    const int n = nt * 128 + ni * 16 + lr;
    const int dom = dom_id[bz];
    const float* src = fcw + (size_t)dom * ((size_t)I_SZ * O_SZ)
                           + (size_t)(kt * 32 + 4 * hi) * O_SZ + n;
    short h[8];
    #pragma unroll
    for (int j = 0; j < 4; ++j) {
        h[j]     = f2bf(src[(size_t)j * O_SZ]);
        h[4 + j] = f2bf(src[(size_t)(16 + j) * O_SZ]);
    }
    *reinterpret_cast<s16x8*>(wt + (size_t)c * 8) =
        *reinterpret_cast<s16x8*>(h);
}

// ------------- bf16 GEMM, 256x256 tile, ring-4, counted vmcnt, 1 barrier/K-step -
// 8 waves: wm = wv>>2 (M half), wn = wv&3 (N quarter). Per wave: 128x64 output.
// Per K-step: [vmcnt(8); s_barrier; stage kt+3; 12 ds_read; 32 MFMA].
// Correctness ledger:
//  - reads of buf[cur]: own stage(kt) drained by vmcnt(8) (FIFO: 12 outstanding,
//    oldest 4 retired); other waves' likewise before the barrier -> global.
//  - stage into buf[(kt+3)&3] == buf[(kt-1)&3]: all waves' READS of that buffer
//    were consumed by kt-1's MFMAs (compiler lgkmcnt) before they reached this
//    barrier -> write-after-read safe.
//  - no barrier between reads and MFMA: waves drift within the region, so one
//    wave's ds_reads overlap other waves' MFMAs (LDS pipe || MFMA pipe), and the
//    compiler's fine-grained lgkmcnt lets MFMA quad 0 start while later reads fly.
__global__ __launch_bounds__(512, 2) void gemm_bf16_256(
        const short* __restrict__ xt, const short* __restrict__ wt,
        const float* __restrict__ bw, const int* __restrict__ dom_id,
        float* __restrict__ out) {
    __shared__ short As[4][8192];   // 4 ring buffers x 16KB (2 m-subtiles x 8KB)
    __shared__ short Bs[4][8192];

    // bijective XCD swizzle: nwg = 1024 = 8 XCDs x 128
    const int bid = blockIdx.x;
    const int swz = (bid & 7) * 128 + (bid >> 3);
    const int bz = swz >> 6;
    const int mb = (swz >> 3) & 7;   // 256-row tile index
    const int nb = swz & 7;          // 256-col tile index

    const short* Abase = xt + (size_t)(bz * 16 + mb * 2) * 64 * 4096;
    const short* Bbase = wt + (size_t)(bz * 16 + nb * 2) * 64 * 4096;

    const int t = threadIdx.x;
    const int wv = t >> 6, l = t & 63;
    const int wm = wv >> 2, wn = wv & 3;
    const int lr = l & 15, hi = l >> 4;
    const int bni = wn >> 1, bsub = (wn & 1) * 4;   // B block / subtile base

    auto stageA = [&](int buf, int kt) {
        #pragma unroll
        for (int i = 0; i < 2; ++i) {
            const int c = wv * 2 + i;              // 0..15
            const int mi = c >> 3, inner = c & 7;
            gload_lds16(Abase + (size_t)(mi * 64 + kt) * 4096 + inner * 512 + l * 8,
                        &As[buf][c * 512]);
        }
    };
    auto stageB = [&](int buf, int kt) {
        #pragma unroll
        for (int i = 0; i < 2; ++i) {
            const int c = wv * 2 + i;
            const int ni = c >> 3, inner = c & 7;
            gload_lds16(Bbase + (size_t)(ni * 64 + kt) * 4096 + inner * 512 + l * 8,
                        &Bs[buf][c * 512]);
        }
    };

    f32x4 acc[8][4] = {};

    // prologue: 12 loads/wave in flight (steps 0,1,2), FIFO order A,B per step
    stageA(0, 0); stageB(0, 0);
    stageA(1, 1); stageB(1, 1);
    stageA(2, 2); stageB(2, 2);

    for (int kt = 0; kt < 64; ++kt) {
        const int cur = kt & 3;
        const int pre = (kt + 3) & 3;                 // stage target buffer
        const int pkt = (kt + 3 > 63) ? 63 : kt + 3;  // dummy re-stage at tail

        asm volatile("s_waitcnt vmcnt(8)" ::: "memory");  // own stage(kt) landed
        asm volatile("s_barrier" ::: "memory");           // global: buf[cur] ready,
                                                          // buf[pre] readers done
        stageA(pre, pkt);
        stageB(pre, pkt);

        s16x8 af[8], bq[4];
        #pragma unroll
        for (int g = 0; g < 4; ++g)
            bq[g] = *reinterpret_cast<const s16x8*>(
                        &Bs[cur][bni * 4096 + (bsub + g) * 512 + l * 8]);
        #pragma unroll
        for (int f = 0; f < 8; ++f)
            af[f] = *reinterpret_cast<const s16x8*>(
                        &As[cur][wm * 4096 + f * 512 + l * 8]);

        __builtin_amdgcn_s_setprio(1);
        #pragma unroll
        for (int f = 0; f < 8; ++f)
            #pragma unroll
            for (int g = 0; g < 4; ++g)
                acc[f][g] = __builtin_amdgcn_mfma_f32_16x16x32_bf16(
                                af[f], bq[g], acc[f][g], 0, 0, 0);
        __builtin_amdgcn_s_setprio(0);
    }

    // retire the tail's outstanding dummy stages before epilogue/endpgm
    asm volatile("s_waitcnt vmcnt(0)" ::: "memory");

    // epilogue: bias + store (wave tile: rows wm*128..+128, cols wn*64..+64)
    const int dom = dom_id[bz];
    const int col0 = nb * 256 + wn * 64;
    float bias[4];
    #pragma unroll
    for (int g = 0; g < 4; ++g)
        bias[g] = bw[dom * O_SZ + col0 + g * 16 + lr];

    const size_t obase = ((size_t)bz * T_SZ + mb * 256 + wm * 128) * O_SZ + col0;
    #pragma unroll
    for (int f = 0; f < 8; ++f) {
        #pragma unroll
        for (int r = 0; r < 4; ++r) {
            const int row = f * 16 + hi * 4 + r;
            float* orow = out + obase + (size_t)row * O_SZ;
            #pragma unroll
            for (int g = 0; g < 4; ++g)
                orow[g * 16 + lr] = acc[f][g][r] + bias[g];
        }
    }
}

// =============== fallback (round-1 kernel) if workspace is too small ===============
constexpr int BM = 128, BN = 128, BK = 32;
constexpr int LDK = 40;
constexpr int NKT = I_SZ / BK;

__global__ __launch_bounds__(256) void dal_gemm(
    const float* __restrict__ x, const int* __restrict__ dom_id,
    const float* __restrict__ fcw, const float* __restrict__ bw,
    float* __restrict__ out)
{
    __shared__ short As[2][BM * LDK];
    __shared__ short Bs[2][BN * LDK];
    const int bz = blockIdx.z;
    const int m0 = blockIdx.y * BM, n0 = blockIdx.x * BN;
    const int dom = dom_id[bz];
    const float* Ag = x + ((size_t)bz * T_SZ + m0) * I_SZ;
    const float* Wg = fcw + (size_t)dom * ((size_t)I_SZ * O_SZ) + n0;
    const int t = threadIdx.x;
    const int am = t >> 3, ac = (t & 7) << 2;
    const int bk = (t >> 5) << 2, bn = (t & 31) << 2;
    const int wv = t >> 6, lane = t & 63;
    const int wr = (wv >> 1) << 6, wc = (wv & 1) << 6;
    const int hi = lane >> 4, lr = lane & 15;
    f32x4 acc[4][4] = {};
    f32x4 ra[4], rb[4];
    auto load_tile = [&](int kb) {
        #pragma unroll
        for (int p = 0; p < 4; ++p)
            ra[p] = *reinterpret_cast<const f32x4*>(Ag + (size_t)(am + 32 * p) * I_SZ + kb + ac);
        #pragma unroll
        for (int r = 0; r < 4; ++r)
            rb[r] = *reinterpret_cast<const f32x4*>(Wg + (size_t)(kb + bk + r) * O_SZ + bn);
    };
    auto store_tile = [&](int buf) {
        #pragma unroll
        for (int p = 0; p < 4; ++p) {
            s16x4 h = { f2bf(ra[p][0]), f2bf(ra[p][1]), f2bf(ra[p][2]), f2bf(ra[p][3]) };
            *reinterpret_cast<s16x4*>(&As[buf][(am + 32 * p) * LDK + ac]) = h;
        }
        #pragma unroll
        for (int i = 0; i < 4; ++i) {
            s16x4 h = { f2bf(rb[0][i]), f2bf(rb[1][i]), f2bf(rb[2][i]), f2bf(rb[3][i]) };
            *reinterpret_cast<s16x4*>(&Bs[buf][(bn + i) * LDK + bk]) = h;
        }
    };
    load_tile(0);
    store_tile(0);
    __syncthreads();
    for (int kt = 0; kt < NKT; ++kt) {
        const int cur = kt & 1;
        if (kt + 1 < NKT) load_tile((kt + 1) * BK);
        s16x8 af[4], bfr[4];
        #pragma unroll
        for (int im = 0; im < 4; ++im) {
            const short* p = &As[cur][(wr + im * 16 + lr) * LDK + 4 * hi];
            s16x4 lo = *reinterpret_cast<const s16x4*>(p);
            s16x4 hh = *reinterpret_cast<const s16x4*>(p + 16);
            af[im] = __builtin_shufflevector(lo, hh, 0, 1, 2, 3, 4, 5, 6, 7);
        }
        #pragma unroll
        for (int in = 0; in < 4; ++in) {
            const short* p = &Bs[cur][(wc + in * 16 + lr) * LDK + 4 * hi];
            s16x4 lo = *reinterpret_cast<const s16x4*>(p);
            s16x4 hh = *reinterpret_cast<const s16x4*>(p + 16);
            bfr[in] = __builtin_shufflevector(lo, hh, 0, 1, 2, 3, 4, 5, 6, 7);
        }
        #pragma unroll
        for (int im = 0; im < 4; ++im)
            #pragma unroll
            for (int in = 0; in < 4; ++in)
                acc[im][in] = __builtin_amdgcn_mfma_f32_16x16x32_bf16(
                                  af[im], bfr[in], acc[im][in], 0, 0, 0);
        if (kt + 1 < NKT) store_tile(cur ^ 1);
        __syncthreads();
    }
    float bias[4];
    #pragma unroll
    for (int in = 0; in < 4; ++in)
        bias[in] = bw[dom * O_SZ + n0 + wc + in * 16 + lr];
    const size_t obase = ((size_t)bz * T_SZ + m0) * O_SZ + n0;
    #pragma unroll
    for (int im = 0; im < 4; ++im) {
        #pragma unroll
        for (int r = 0; r < 4; ++r) {
            const int row = wr + im * 16 + hi * 4 + r;
            float* orow = out + obase + (size_t)row * O_SZ;
            #pragma unroll
            for (int in = 0; in < 4; ++in)
                orow[wc + in * 16 + lr] = acc[im][in][r] + bias[in];
        }
    }
}

extern "C" void kernel_launch(void* const* d_in, const int* in_sizes, int n_in,
                              void* d_out, int out_size, void* d_ws, size_t ws_size,
                              hipStream_t stream) {
    const float* x   = (const float*)d_in[0];
    const int*   dom = (const int*)d_in[1];
    const float* fcw = (const float*)d_in[2];
    const float* bw  = (const float*)d_in[3];
    float* out = (float*)d_out;
    const int B = in_sizes[1];   // 16

    if (ws_size >= WS_NEEDED && B == B_MAX) {
        short* xt = (short*)d_ws;
        short* wt = xt + XT_ELEMS;
        const int chunks = B * 16 * 64 * 512;             // 8,388,608
        convA<<<chunks / 256, 256, 0, stream>>>(x, xt);
        convB<<<chunks / 256, 256, 0, stream>>>(fcw, dom, wt);
        gemm_bf16_256<<<dim3(1024), dim3(512), 0, stream>>>(xt, wt, bw, dom, out);
    } else {
        dim3 grid(O_SZ / BN, T_SZ / BM, B);
        dal_gemm<<<grid, dim3(256), 0, stream>>>(x, dom, fcw, bw, out);
    }
}

// Round 8
// 511.825 us; speedup vs baseline: 1.0443x; 1.0443x over previous
//
#include <hip/hip_runtime.h>
#include <hip/hip_bf16.h>
#include <stdint.h>

typedef __attribute__((ext_vector_type(4))) float  f32x4;
typedef __attribute__((ext_vector_type(8))) short  s16x8;
typedef __attribute__((ext_vector_type(4))) short  s16x4;

constexpr int I_SZ = 2048;
constexpr int O_SZ = 2048;
constexpr int T_SZ = 2048;
constexpr int B_MAX = 16;

// pre-tiled layout: per (bz, mtile/ntile of 128, ktile of 32): 8KB block =
// 8 subtiles (16 rows each) x 1KB; within a subtile, byte offset l*16 holds
// fragment of lane l: row = l&15, k = 4*(l>>4) + {0..3} and 16 + 4*(l>>4) + {0..3}
constexpr size_t XT_ELEMS = (size_t)B_MAX * T_SZ * I_SZ;         // 67,108,864 shorts
constexpr size_t WT_ELEMS = (size_t)B_MAX * I_SZ * O_SZ;
constexpr size_t WS_NEEDED = (XT_ELEMS + WT_ELEMS) * sizeof(short); // 256 MB

__device__ __forceinline__ short f2bf(float f) {
    __hip_bfloat16 h = __float2bfloat16(f);
    return *reinterpret_cast<short*>(&h);
}

__device__ __forceinline__ void gload_lds16(const void* g, void* l) {
    __builtin_amdgcn_global_load_lds(
        (const __attribute__((address_space(1))) unsigned int*)g,
        (__attribute__((address_space(3))) unsigned int*)l, 16, 0, 0);
}

// ---------------- conversion: x fp32 [B][T][I] -> pre-tiled bf16 ----------------
__global__ __launch_bounds__(256) void convA(const float* __restrict__ x,
                                             short* __restrict__ xt) {
    const int c = blockIdx.x * 256 + threadIdx.x;    // 16B-chunk id
    const int l  = c & 63;
    const int mi = (c >> 6) & 7;
    const int kt = (c >> 9) & 63;
    const int rest = c >> 15;                        // (bz*16 + mt)
    const int mt = rest & 15, bz = rest >> 4;
    const int lr = l & 15, hi = l >> 4;
    const int m = mt * 128 + mi * 16 + lr;
    const float* src = x + ((size_t)(bz * T_SZ + m)) * I_SZ + kt * 32 + 4 * hi;
    f32x4 a = *reinterpret_cast<const f32x4*>(src);
    f32x4 b = *reinterpret_cast<const f32x4*>(src + 16);
    s16x8 h = { f2bf(a[0]), f2bf(a[1]), f2bf(a[2]), f2bf(a[3]),
                f2bf(b[0]), f2bf(b[1]), f2bf(b[2]), f2bf(b[3]) };
    *reinterpret_cast<s16x8*>(xt + (size_t)c * 8) = h;
}

// ------- conversion: W fp32 [dom][I][O] gathered+transposed -> pre-tiled bf16 ----
__global__ __launch_bounds__(256) void convB(const float* __restrict__ fcw,
                                             const int* __restrict__ dom_id,
                                             short* __restrict__ wt) {
    const int c = blockIdx.x * 256 + threadIdx.x;
    const int l  = c & 63;
    const int ni = (c >> 6) & 7;
    const int kt = (c >> 9) & 63;
    const int rest = c >> 15;                        // (bz*16 + nt)
    const int nt = rest & 15, bz = rest >> 4;
    const int lr = l & 15, hi = l >> 4;
    const int n = nt * 128 + ni * 16 + lr;
    const int dom = dom_id[bz];
    const float* src = fcw + (size_t)dom * ((size_t)I_SZ * O_SZ)
                           + (size_t)(kt * 32 + 4 * hi) * O_SZ + n;
    short h[8];
    #pragma unroll
    for (int j = 0; j < 4; ++j) {
        h[j]     = f2bf(src[(size_t)j * O_SZ]);
        h[4 + j] = f2bf(src[(size_t)(16 + j) * O_SZ]);
    }
    *reinterpret_cast<s16x8*>(wt + (size_t)c * 8) =
        *reinterpret_cast<s16x8*>(h);
}

// -------- bf16 GEMM, 256x256 tile, BK=64, m201-style 4-phase K-tile schedule ----
// 8 waves (wm in {0,1} M-half, wn in {0..3} N-quarter), wave output 128x64.
// LDS: 2 double-buffers x (A 32KB + B 32KB) = 128 KB, pre-tiled conflict-free.
// Per K64-tile T (buf d=T&1), 4 phases; stage event p of tile T+1 at phase p:
//   P0: [rd bq-k0 x4, af0-3-k0 x4; stage A-k0(T+1); BAR; 16 MFMA; BAR]
//   P1: [rd af4-7-k0 x4;           stage B-k0(T+1); vmcnt(4); BAR; 16 MFMA; BAR]
//   P2: [rd bq-k1 x4, af0-3-k1 x4; stage A-k1(T+1); BAR; 16 MFMA; BAR]
//   P3: [rd af4-7-k1 x4;           stage B-k1(T+1); vmcnt(4); BAR; 16 MFMA; BAR]
// vmcnt ledger (per-wave FIFO, 2 gloads/event): at each vmcnt(4) point exactly 4
// events (8 instrs) are outstanding; waiting to 4 retires the 2 events that the
// next two phases read. Never drains to 0 in the main loop. Write-after-read:
// stages target buf d^1, last read during tile T-1 (8 barriers earlier).
__global__ __launch_bounds__(512, 2) void gemm_bf16_256(
        const short* __restrict__ xt, const short* __restrict__ wt,
        const float* __restrict__ bw, const int* __restrict__ dom_id,
        float* __restrict__ out) {
    __shared__ short As[2][16384];   // [d][kh*8192 + chunk*512 + ...]
    __shared__ short Bs[2][16384];

    // bijective XCD swizzle: nwg = 1024 = 8 XCDs x 128
    const int bid = blockIdx.x;
    const int swz = (bid & 7) * 128 + (bid >> 3);
    const int bz = swz >> 6;
    const int mb = (swz >> 3) & 7;   // 256-row tile index
    const int nb = swz & 7;          // 256-col tile index

    const short* Abase = xt + (size_t)(bz * 16 + mb * 2) * 64 * 4096;
    const short* Bbase = wt + (size_t)(bz * 16 + nb * 2) * 64 * 4096;

    const int t = threadIdx.x;
    const int wv = t >> 6, l = t & 63;
    const int wm = wv >> 2, wn = wv & 3;
    const int lr = l & 15, hi = l >> 4;
    const int bni = wn >> 1, bsub = (wn & 1) * 4;   // B block / subtile base

    // stage one 16KB event: A (or B) panel, one k32 half of tile T
    auto stageA = [&](int d, int kh, int T) {
        const int kt = 2 * T + kh;
        #pragma unroll
        for (int i = 0; i < 2; ++i) {
            const int c = wv * 2 + i;              // 0..15
            const int mi = c >> 3, inner = c & 7;
            gload_lds16(Abase + (size_t)(mi * 64 + kt) * 4096 + inner * 512 + l * 8,
                        &As[d][kh * 8192 + c * 512]);
        }
    };
    auto stageB = [&](int d, int kh, int T) {
        const int kt = 2 * T + kh;
        #pragma unroll
        for (int i = 0; i < 2; ++i) {
            const int c = wv * 2 + i;
            const int ni = c >> 3, inner = c & 7;
            gload_lds16(Bbase + (size_t)(ni * 64 + kt) * 4096 + inner * 512 + l * 8,
                        &Bs[d][kh * 8192 + c * 512]);
        }
    };

    f32x4 acc[8][4] = {};

    auto rdA = [&](int d, int kh, int f) {
        return *reinterpret_cast<const s16x8*>(
                   &As[d][kh * 8192 + wm * 4096 + f * 512 + l * 8]);
    };
    auto rdB = [&](int d, int kh, int g) {
        return *reinterpret_cast<const s16x8*>(
                   &Bs[d][kh * 8192 + bni * 4096 + (bsub + g) * 512 + l * 8]);
    };

    auto mfma16 = [&](const s16x8* af4, const s16x8* bq4, int fo) {
        __builtin_amdgcn_s_setprio(1);
        #pragma unroll
        for (int f = 0; f < 4; ++f)
            #pragma unroll
            for (int g = 0; g < 4; ++g)
                acc[fo + f][g] = __builtin_amdgcn_mfma_f32_16x16x32_bf16(
                                     af4[f], bq4[g], acc[fo + f][g], 0, 0, 0);
        __builtin_amdgcn_s_setprio(0);
    };

    // prologue: stage tile 0 fully, drain, barrier
    stageA(0, 0, 0); stageB(0, 0, 0); stageA(0, 1, 0); stageB(0, 1, 0);
    asm volatile("s_waitcnt vmcnt(0)" ::: "memory");
    asm volatile("s_barrier" ::: "memory");

    for (int T = 0; T < 32; ++T) {
        const int d = T & 1, nd = d ^ 1;
        const int nT = (T + 1 < 32) ? T + 1 : 31;   // dummy tail keeps ledger uniform
        s16x8 bq0[4], bq1[4], af0[4], af1[4];

        // ---- P0: k0, m-frags 0-3 ----
        #pragma unroll
        for (int g = 0; g < 4; ++g) bq0[g] = rdB(d, 0, g);
        #pragma unroll
        for (int f = 0; f < 4; ++f) af0[f] = rdA(d, 0, f);
        stageA(nd, 0, nT);
        asm volatile("s_barrier" ::: "memory");
        mfma16(af0, bq0, 0);
        asm volatile("s_barrier" ::: "memory");

        // ---- P1: k0, m-frags 4-7 ----
        #pragma unroll
        for (int f = 0; f < 4; ++f) af1[f] = rdA(d, 0, 4 + f);
        stageB(nd, 0, nT);
        asm volatile("s_waitcnt vmcnt(4)" ::: "memory");  // A-k1(T), B-k1(T) landed
        asm volatile("s_barrier" ::: "memory");
        mfma16(af1, bq0, 4);
        asm volatile("s_barrier" ::: "memory");

        // ---- P2: k1, m-frags 0-3 ----
        #pragma unroll
        for (int g = 0; g < 4; ++g) bq1[g] = rdB(d, 1, g);
        #pragma unroll
        for (int f = 0; f < 4; ++f) af0[f] = rdA(d, 1, f);
        stageA(nd, 1, nT);
        asm volatile("s_barrier" ::: "memory");
        mfma16(af0, bq1, 0);
        asm volatile("s_barrier" ::: "memory");

        // ---- P3: k1, m-frags 4-7 ----
        #pragma unroll
        for (int f = 0; f < 4; ++f) af1[f] = rdA(d, 1, 4 + f);
        stageB(nd, 1, nT);
        asm volatile("s_waitcnt vmcnt(4)" ::: "memory");  // A-k0(T+1), B-k0(T+1) landed
        asm volatile("s_barrier" ::: "memory");
        mfma16(af1, bq1, 4);
        asm volatile("s_barrier" ::: "memory");
    }

    // retire the tail's outstanding dummy stages before epilogue/endpgm
    asm volatile("s_waitcnt vmcnt(0)" ::: "memory");

    // epilogue: bias + store (wave tile: rows wm*128..+128, cols wn*64..+64)
    const int dom = dom_id[bz];
    const int col0 = nb * 256 + wn * 64;
    float bias[4];
    #pragma unroll
    for (int g = 0; g < 4; ++g)
        bias[g] = bw[dom * O_SZ + col0 + g * 16 + lr];

    const size_t obase = ((size_t)bz * T_SZ + mb * 256 + wm * 128) * O_SZ + col0;
    #pragma unroll
    for (int f = 0; f < 8; ++f) {
        #pragma unroll
        for (int r = 0; r < 4; ++r) {
            const int row = f * 16 + hi * 4 + r;
            float* orow = out + obase + (size_t)row * O_SZ;
            #pragma unroll
            for (int g = 0; g < 4; ++g)
                orow[g * 16 + lr] = acc[f][g][r] + bias[g];
        }
    }
}

// =============== fallback (round-1 kernel) if workspace is too small ===============
constexpr int BM = 128, BN = 128, BK = 32;
constexpr int LDK = 40;
constexpr int NKT = I_SZ / BK;

__global__ __launch_bounds__(256) void dal_gemm(
    const float* __restrict__ x, const int* __restrict__ dom_id,
    const float* __restrict__ fcw, const float* __restrict__ bw,
    float* __restrict__ out)
{
    __shared__ short As[2][BM * LDK];
    __shared__ short Bs[2][BN * LDK];
    const int bz = blockIdx.z;
    const int m0 = blockIdx.y * BM, n0 = blockIdx.x * BN;
    const int dom = dom_id[bz];
    const float* Ag = x + ((size_t)bz * T_SZ + m0) * I_SZ;
    const float* Wg = fcw + (size_t)dom * ((size_t)I_SZ * O_SZ) + n0;
    const int t = threadIdx.x;
    const int am = t >> 3, ac = (t & 7) << 2;
    const int bk = (t >> 5) << 2, bn = (t & 31) << 2;
    const int wv = t >> 6, lane = t & 63;
    const int wr = (wv >> 1) << 6, wc = (wv & 1) << 6;
    const int hi = lane >> 4, lr = lane & 15;
    f32x4 acc[4][4] = {};
    f32x4 ra[4], rb[4];
    auto load_tile = [&](int kb) {
        #pragma unroll
        for (int p = 0; p < 4; ++p)
            ra[p] = *reinterpret_cast<const f32x4*>(Ag + (size_t)(am + 32 * p) * I_SZ + kb + ac);
        #pragma unroll
        for (int r = 0; r < 4; ++r)
            rb[r] = *reinterpret_cast<const f32x4*>(Wg + (size_t)(kb + bk + r) * O_SZ + bn);
    };
    auto store_tile = [&](int buf) {
        #pragma unroll
        for (int p = 0; p < 4; ++p) {
            s16x4 h = { f2bf(ra[p][0]), f2bf(ra[p][1]), f2bf(ra[p][2]), f2bf(ra[p][3]) };
            *reinterpret_cast<s16x4*>(&As[buf][(am + 32 * p) * LDK + ac]) = h;
        }
        #pragma unroll
        for (int i = 0; i < 4; ++i) {
            s16x4 h = { f2bf(rb[0][i]), f2bf(rb[1][i]), f2bf(rb[2][i]), f2bf(rb[3][i]) };
            *reinterpret_cast<s16x4*>(&Bs[buf][(bn + i) * LDK + bk]) = h;
        }
    };
    load_tile(0);
    store_tile(0);
    __syncthreads();
    for (int kt = 0; kt < NKT; ++kt) {
        const int cur = kt & 1;
        if (kt + 1 < NKT) load_tile((kt + 1) * BK);
        s16x8 af[4], bfr[4];
        #pragma unroll
        for (int im = 0; im < 4; ++im) {
            const short* p = &As[cur][(wr + im * 16 + lr) * LDK + 4 * hi];
            s16x4 lo = *reinterpret_cast<const s16x4*>(p);
            s16x4 hh = *reinterpret_cast<const s16x4*>(p + 16);
            af[im] = __builtin_shufflevector(lo, hh, 0, 1, 2, 3, 4, 5, 6, 7);
        }
        #pragma unroll
        for (int in = 0; in < 4; ++in) {
            const short* p = &Bs[cur][(wc + in * 16 + lr) * LDK + 4 * hi];
            s16x4 lo = *reinterpret_cast<const s16x4*>(p);
            s16x4 hh = *reinterpret_cast<const s16x4*>(p + 16);
            bfr[in] = __builtin_shufflevector(lo, hh, 0, 1, 2, 3, 4, 5, 6, 7);
        }
        #pragma unroll
        for (int im = 0; im < 4; ++im)
            #pragma unroll
            for (int in = 0; in < 4; ++in)
                acc[im][in] = __builtin_amdgcn_mfma_f32_16x16x32_bf16(
                                  af[im], bfr[in], acc[im][in], 0, 0, 0);
        if (kt + 1 < NKT) store_tile(cur ^ 1);
        __syncthreads();
    }
    float bias[4];
    #pragma unroll
    for (int in = 0; in < 4; ++in)
        bias[in] = bw[dom * O_SZ + n0 + wc + in * 16 + lr];
    const size_t obase = ((size_t)bz * T_SZ + m0) * O_SZ + n0;
    #pragma unroll
    for (int im = 0; im < 4; ++im) {
        #pragma unroll
        for (int r = 0; r < 4; ++r) {
            const int row = wr + im * 16 + hi * 4 + r;
            float* orow = out + obase + (size_t)row * O_SZ;
            #pragma unroll
            for (int in = 0; in < 4; ++in)
                orow[wc + in * 16 + lr] = acc[im][in][r] + bias[in];
        }
    }
}

extern "C" void kernel_launch(void* const* d_in, const int* in_sizes, int n_in,
                              void* d_out, int out_size, void* d_ws, size_t ws_size,
                              hipStream_t stream) {
    const float* x   = (const float*)d_in[0];
    const int*   dom = (const int*)d_in[1];
    const float* fcw = (const float*)d_in[2];
    const float* bw  = (const float*)d_in[3];
    float* out = (float*)d_out;
    const int B = in_sizes[1];   // 16

    if (ws_size >= WS_NEEDED && B == B_MAX) {
        short* xt = (short*)d_ws;
        short* wt = xt + XT_ELEMS;
        const int chunks = B * 16 * 64 * 512;             // 8,388,608
        convA<<<chunks / 256, 256, 0, stream>>>(x, xt);
        convB<<<chunks / 256, 256, 0, stream>>>(fcw, dom, wt);
        gemm_bf16_256<<<dim3(1024), dim3(512), 0, stream>>>(xt, wt, bw, dom, out);
    } else {
        dim3 grid(O_SZ / BN, T_SZ / BM, B);
        dal_gemm<<<grid, dim3(256), 0, stream>>>(x, dom, fcw, bw, out);
    }
}